// Round 1
// 224.995 us; speedup vs baseline: 1.3080x; 1.3080x over previous
//
#include <hip/hip_runtime.h>

// NetVLAD — round 3: occupancy + barrier restructure.
// B=32, N=4096, D=256, K=128, Dc=64.
//
// Phase1: grid 256 (8 blocks/batch, 512 rows), 512 thr (8 waves), 1 blk/CU,
//   2 waves/SIMD. Waves: rt = w>>2 (row-tile), cg = w&3 (col-group of 3 tiles:
//   cg0:Wa0-2, cg1:Wa3-5, cg2:Wa6,7+W1_0, cg3:W1_1-3).
//   Wa/W1 B-frags live in REGISTERS (wf[3][8], 96 VGPR) — no LDS B reads in loop.
//   GEMM3 folded out algebraically: agg = (A^T H) W2^T + mass*b2; the loop
//   accumulates U = A^T H into gacc; U@W2^T runs once at flush; mass*b2 in phase2.
//   Softmax: one (max,sum) pair exchange -> 2 barriers/iter (was 4).
// Phase2: vlad = agg + mass*(b2 - centroid), L2-normalize.
//
// MFMA 16x16x32 layouts (m89/m120-verified):
//   A: lane holds A[m=lane&15][k=(lane>>4)*8+j]
//   B: lane holds B[k=(lane>>4)*8+j][n=lane&15]
//   C/D: lane holds D[row=(lane>>4)*4+reg][col=lane&15]

#define B_   32
#define N_   4096
#define D_   256
#define K_   128
#define DC_  64
#define ITERS 16          // 32-row iters per block (512 rows)
#define NEG  0.01f

typedef __attribute__((ext_vector_type(8))) short bf16x8;
typedef __attribute__((ext_vector_type(4))) float f32x4;

// LDS byte map (total 37888)
#define XF_OFF   0        // X A-frags: 2rt x 8ks x 64L x 16B = 16384 ; reused as U-frag scratch at flush
#define AT_OFF   16384    // assign A-frags: 8 k-tiles x 1024
#define HB_OFF   24576    // H B-frags: 4 e-tiles x 1024
#define W2F_OFF  28672    // W2 B-frags: 4ct x 2ke x 1024 = 8192
#define MS_OFF   36864    // (max,sum) float2 [2rt][4cg pad][16row] = 1024
#define LDS_BYTES 37888

__device__ __forceinline__ unsigned short f2bf(float x) {
  union { float f; unsigned u; } v; v.f = x;
  unsigned r = v.u + 0x7fffu + ((v.u >> 16) & 1u);
  return (unsigned short)(r >> 16);
}
__device__ __forceinline__ unsigned pack2(float a, float b) {
  return (unsigned)f2bf(a) | ((unsigned)f2bf(b) << 16);
}
__device__ __forceinline__ bf16x8 ldf(const char* s, int off) {
  return *reinterpret_cast<const bf16x8*>(s + off);
}

__global__ __launch_bounds__(512, 2)
void netvlad_phase1(const float* __restrict__ desc, const float* __restrict__ W1,
                    const float* __restrict__ b1, const float* __restrict__ W2,
                    const float* __restrict__ Wa, const float* __restrict__ ba,
                    float* __restrict__ agg, float* __restrict__ mass)
{
  extern __shared__ char smem[];
  const int t    = threadIdx.x;
  const int b    = blockIdx.x >> 3;
  const int blk  = blockIdx.x & 7;
  const int w    = t >> 6;         // wave 0..7
  const int lane = t & 63;
  const int li   = lane & 15;
  const int quad = lane >> 4;
  const int rt   = w >> 2;         // row-tile 0/1
  const int cg   = w & 3;          // col-group
  const int nWa  = (cg < 2) ? 3 : (cg == 2 ? 2 : 0);

  // ---- W2 -> LDS B-frags (once; used only at flush) ----
  {
    int L = t & 63;
    int row = ((t >> 7) << 4) + (L & 15);
    int col = (((t >> 6) & 1) << 5) + ((L >> 4) << 3);
    const float* src = W2 + row * DC_ + col;
    float4 a = *(const float4*)src, c = *(const float4*)(src + 4);
    uint4 o; o.x = pack2(a.x, a.y); o.y = pack2(a.z, a.w);
    o.z = pack2(c.x, c.y); o.w = pack2(c.z, c.w);
    *reinterpret_cast<uint4*>(smem + W2F_OFF + t * 16) = o;
  }

  // ---- Wa/W1 B-frags -> registers: 3 tiles x 8 ks = 96 VGPR/wave ----
  bf16x8 wf[3][8];
  #pragma unroll
  for (int j = 0; j < 3; ++j) {
    const int g = cg * 3 + j;   // 0..7 = Wa tiles, 8..11 = W1 tiles
    const float* wrow = (g < 8) ? (Wa + (size_t)(g * 16 + li) * D_)
                                : (W1 + (size_t)((g - 8) * 16 + li) * D_);
    #pragma unroll
    for (int ks = 0; ks < 8; ++ks) {
      const float* s = wrow + ks * 32 + quad * 8;
      float4 a = *(const float4*)s, c = *(const float4*)(s + 4);
      union { uint4 u; bf16x8 v; } cv;
      cv.u.x = pack2(a.x, a.y); cv.u.y = pack2(a.z, a.w);
      cv.u.z = pack2(c.x, c.y); cv.u.w = pack2(c.z, c.w);
      wf[j][ks] = cv.v;
    }
  }

  float biasr[3];
  #pragma unroll
  for (int j = 0; j < 3; ++j) {
    const int g = cg * 3 + j;
    biasr[j] = (g < 8) ? ba[g * 16 + li] : b1[(g - 8) * 16 + li];
  }

  // ---- X staging: global prefetch regs + frag-order LDS write (1024 chunks) ----
  float4 xp[4];
  auto issueX = [&](int itn) {
    const int n0 = blk * 512 + itn * 32;
    #pragma unroll
    for (int i = 0; i < 2; ++i) {
      int p = t + i * 512;
      int L = p & 63;
      const float* src = desc + ((size_t)b * N_ + n0 + ((p >> 9) << 4) + (L & 15)) * D_
                       + (((p >> 6) & 7) << 5) + ((L >> 4) << 3);
      xp[2 * i]     = *(const float4*)src;
      xp[2 * i + 1] = *(const float4*)(src + 4);
    }
  };
  auto writeX = [&]() {
    #pragma unroll
    for (int i = 0; i < 2; ++i) {
      uint4 o;
      o.x = pack2(xp[2 * i].x,     xp[2 * i].y);
      o.y = pack2(xp[2 * i].z,     xp[2 * i].w);
      o.z = pack2(xp[2 * i + 1].x, xp[2 * i + 1].y);
      o.w = pack2(xp[2 * i + 1].z, xp[2 * i + 1].w);
      *reinterpret_cast<uint4*>(smem + XF_OFF + (t + i * 512) * 16) = o;
    }
  };

  issueX(0); writeX(); issueX(1);

  f32x4 gacc[4];                       // U = A^T H accumulator: k-tile w, 4 e-tiles
  #pragma unroll
  for (int nt = 0; nt < 4; ++nt) gacc[nt] = (f32x4){0.f, 0.f, 0.f, 0.f};
  float massA[3] = {0.f, 0.f, 0.f};

  __syncthreads();   // W2F + XF_0 ready

  for (int it = 0; it < ITERS; ++it) {
    // ---- GEMM1/2: logits + h, B-operands from registers ----
    f32x4 accT[3];
    #pragma unroll
    for (int j = 0; j < 3; ++j) accT[j] = (f32x4){0.f, 0.f, 0.f, 0.f};
    #pragma unroll
    for (int ks = 0; ks < 8; ++ks) {
      bf16x8 xa = ldf(smem, XF_OFF + ((rt * 8 + ks) * 64 + lane) * 16);
      #pragma unroll
      for (int j = 0; j < 3; ++j)
        accT[j] = __builtin_amdgcn_mfma_f32_16x16x32_bf16(xa, wf[j][ks], accT[j], 0, 0, 0);
    }
    #pragma unroll
    for (int j = 0; j < 3; ++j) {
      accT[j][0] += biasr[j]; accT[j][1] += biasr[j];
      accT[j][2] += biasr[j]; accT[j][3] += biasr[j];
    }

    // ---- local softmax: per-row (max, sum_exp) within this wave's group ----
    float m4[4], s4[4];
    if (nWa) {
      #pragma unroll
      for (int r = 0; r < 4; ++r) {
        float m = -1e30f;
        #pragma unroll
        for (int j = 0; j < 3; ++j) if (j < nWa) m = fmaxf(m, accT[j][r]);
        #pragma unroll
        for (int off = 1; off < 16; off <<= 1) m = fmaxf(m, __shfl_xor(m, off, 64));
        float s = 0.f;
        #pragma unroll
        for (int j = 0; j < 3; ++j) if (j < nWa) {
          float e = __expf(accT[j][r] - m); accT[j][r] = e; s += e;
        }
        #pragma unroll
        for (int off = 1; off < 16; off <<= 1) s += __shfl_xor(s, off, 64);
        m4[r] = m; s4[r] = s;
      }
      if (li == 0) {
        #pragma unroll
        for (int r = 0; r < 4; ++r) {
          float2 v; v.x = m4[r]; v.y = s4[r];
          *reinterpret_cast<float2*>(smem + MS_OFF + ((rt * 4 + cg) * 16 + quad * 4 + r) * 8) = v;
        }
      }
    }
    __syncthreads();  // (1) XF reads done; (m,s) pairs visible

    // stage next X tile (XF free), prefetch the one after
    if (it + 1 < ITERS) { writeX(); if (it + 2 < ITERS) issueX(it + 2); }

    const int Lt  = li + 16 * (rt * 2 + (quad >> 1));
    const int sub = quad & 1;

    if (nWa) {
      // combine 3 groups' (m,s): scale = e^{m_own-M} / S_total
      const int g1 = (cg + 1) % 3, g2 = (cg + 2) % 3;
      float sc[4];
      #pragma unroll
      for (int r = 0; r < 4; ++r) {
        const int row = quad * 4 + r;
        float2 o1 = *reinterpret_cast<const float2*>(smem + MS_OFF + ((rt * 4 + g1) * 16 + row) * 8);
        float2 o2 = *reinterpret_cast<const float2*>(smem + MS_OFF + ((rt * 4 + g2) * 16 + row) * 8);
        float M  = fmaxf(m4[r], fmaxf(o1.x, o2.x));
        float e0 = __expf(m4[r] - M);
        float S  = s4[r] * e0 + o1.y * __expf(o1.x - M) + o2.y * __expf(o2.x - M);
        sc[r] = e0 / S;
      }
      #pragma unroll
      for (int j = 0; j < 3; ++j) if (j < nWa) {
        const int g = cg * 3 + j;
        float a0 = accT[j][0] * sc[0], a1 = accT[j][1] * sc[1];
        float a2 = accT[j][2] * sc[2], a3 = accT[j][3] * sc[3];
        massA[j] += a0 + a1 + a2 + a3;
        uint2 pk; pk.x = pack2(a0, a1); pk.y = pack2(a2, a3);
        *reinterpret_cast<uint2*>(smem + AT_OFF + g * 1024 + Lt * 16 + sub * 8) = pk;
      }
    }
    if (cg >= 2) {
      // h tiles -> LeakyReLU -> HB (B-frag layout: k=row, n=e)
      #pragma unroll
      for (int j = 0; j < 3; ++j) {
        const int g = cg * 3 + j;
        if (g >= 8) {
          const int ce = g - 8;
          float h0 = accT[j][0], h1 = accT[j][1], h2 = accT[j][2], h3 = accT[j][3];
          h0 = h0 >= 0.f ? h0 : NEG * h0;  h1 = h1 >= 0.f ? h1 : NEG * h1;
          h2 = h2 >= 0.f ? h2 : NEG * h2;  h3 = h3 >= 0.f ? h3 : NEG * h3;
          uint2 pk; pk.x = pack2(h0, h1); pk.y = pack2(h2, h3);
          *reinterpret_cast<uint2*>(smem + HB_OFF + ce * 1024 + Lt * 16 + sub * 8) = pk;
        }
      }
    }
    __syncthreads();  // (2) AT + HB ready (XF_{it+1} writes also drained)

    // ---- U accumulation: U[k-tile w] += A^T H over this iter's 32 rows ----
    bf16x8 af = ldf(smem, AT_OFF + w * 1024 + lane * 16);
    #pragma unroll
    for (int nt = 0; nt < 4; ++nt) {
      bf16x8 hb = ldf(smem, HB_OFF + nt * 1024 + lane * 16);
      gacc[nt] = __builtin_amdgcn_mfma_f32_16x16x32_bf16(af, hb, gacc[nt], 0, 0, 0);
    }
    // next iter's AT/HB writes happen after its barrier (1); safe.
  }

  // ---- flush: agg_partial = U @ W2^T (once per block) ----
  // scatter U (C-layout) into XF region as A-frags; wave-private, no barrier.
  #pragma unroll
  for (int nt = 0; nt < 4; ++nt) {
    const int ke = nt >> 1;
    const int Lc = quad * 4 + 16 * (((nt & 1) << 1) + (li >> 3));
    const int jj = li & 7;
    #pragma unroll
    for (int r = 0; r < 4; ++r)
      *reinterpret_cast<unsigned short*>(
        smem + XF_OFF + (w * 2 + ke) * 1024 + (Lc + r) * 16 + jj * 2) = f2bf(gacc[nt][r]);
  }

  f32x4 wacc[4];
  #pragma unroll
  for (int nt = 0; nt < 4; ++nt) wacc[nt] = (f32x4){0.f, 0.f, 0.f, 0.f};
  #pragma unroll
  for (int ke = 0; ke < 2; ++ke) {
    bf16x8 uf = ldf(smem, XF_OFF + (w * 2 + ke) * 1024 + lane * 16);
    #pragma unroll
    for (int nt = 0; nt < 4; ++nt) {
      bf16x8 w2f = ldf(smem, W2F_OFF + ((nt * 2 + ke) * 64 + lane) * 16);
      wacc[nt] = __builtin_amdgcn_mfma_f32_16x16x32_bf16(uf, w2f, wacc[nt], 0, 0, 0);
    }
  }

  float* aggB = agg + (size_t)b * (K_ * DC_);
  #pragma unroll
  for (int nt = 0; nt < 4; ++nt)
    #pragma unroll
    for (int r = 0; r < 4; ++r)
      atomicAdd(&aggB[(w * 16 + quad * 4 + r) * DC_ + nt * 16 + li], wacc[nt][r]);

  // ---- mass flush ----
  #pragma unroll
  for (int j = 0; j < 3; ++j) if (j < nWa) {
    float v = massA[j];
    v += __shfl_xor(v, 16, 64);
    v += __shfl_xor(v, 32, 64);
    if (lane < 16) atomicAdd(&mass[b * K_ + (cg * 3 + j) * 16 + li], v);
  }
}

__global__ __launch_bounds__(1024)
void netvlad_phase2(const float* __restrict__ agg, const float* __restrict__ mass,
                    const float* __restrict__ b2, const float* __restrict__ centroid,
                    float* __restrict__ out)
{
  __shared__ float v[K_ * DC_];
  __shared__ float red[16];
  const int b = blockIdx.x, t = threadIdx.x;
  float ss = 0.f;
  for (int idx = t; idx < K_ * DC_; idx += 1024) {
    int k = idx >> 6, d = idx & 63;
    // vlad = U_tot@W2^T + mass*b2 - mass*centroid
    float val = agg[(size_t)b * K_ * DC_ + idx] + mass[b * K_ + k] * (b2[d] - centroid[idx]);
    v[idx] = val;
    ss += val * val;
  }
  #pragma unroll
  for (int off = 32; off > 0; off >>= 1) ss += __shfl_down(ss, off, 64);
  if ((t & 63) == 0) red[t >> 6] = ss;
  __syncthreads();
  if (t == 0) {
    float s = 0.f;
    #pragma unroll
    for (int i = 0; i < 16; ++i) s += red[i];
    red[0] = 1.0f / fmaxf(sqrtf(s), 1e-12f);
  }
  __syncthreads();
  float inv = red[0];
  for (int idx = t; idx < K_ * DC_; idx += 1024)
    out[(size_t)b * K_ * DC_ + idx] = v[idx] * inv;
}

extern "C" void kernel_launch(void* const* d_in, const int* in_sizes, int n_in,
                              void* d_out, int out_size, void* d_ws, size_t ws_size,
                              hipStream_t stream) {
  const float* desc     = (const float*)d_in[0];
  const float* W1       = (const float*)d_in[1];
  const float* b1       = (const float*)d_in[2];
  const float* W2       = (const float*)d_in[3];
  const float* b2       = (const float*)d_in[4];
  const float* Wa       = (const float*)d_in[5];
  const float* ba       = (const float*)d_in[6];
  const float* centroid = (const float*)d_in[7];
  float* out = (float*)d_out;

  float* agg  = (float*)d_ws;                 // B*K*Dc
  float* mass = agg + B_ * K_ * DC_;          // B*K
  size_t zbytes = (size_t)(B_ * K_ * DC_ + B_ * K_) * sizeof(float);
  hipMemsetAsync(d_ws, 0, zbytes, stream);

  hipFuncSetAttribute(reinterpret_cast<const void*>(netvlad_phase1),
                      hipFuncAttributeMaxDynamicSharedMemorySize, LDS_BYTES);

  netvlad_phase1<<<dim3(B_ * 8), dim3(512), LDS_BYTES, stream>>>(
      desc, W1, b1, W2, Wa, ba, agg, mass);
  netvlad_phase2<<<dim3(B_), dim3(1024), 0, stream>>>(agg, mass, b2, centroid, out);
}